// Round 2
// baseline (44.448 us; speedup 1.0000x reference)
//
#include <hip/hip_runtime.h>
#include <stdint.h>

// Problem constants (fixed by the reference setup)
#define B_ 256
#define V_ 128000
#define T_ 16
#define K_ 64
#define NEG_INF_ (-1e30f)

#define NBUCK 3072     // fine histogram buckets over raw value range [2.0, 16.0)
#define CAP   1024     // candidate buffer capacity (E[count]=173 at thr 3.0)
#define NT    1024     // threads per block (16 waves)

__device__ __forceinline__ uint32_t rotl32(uint32_t x, uint32_t d) {
  return (x << d) | (x >> (32u - d));
}

// JAX threefry2x32, PARTITIONABLE scheme (jax_threefry_partitionable=True,
// default since JAX 0.4.30). For key = jax.random.key(42) -> (k1,k2)=(0,42):
// counters come from iota_2x32_shape(shape): element with flat index f uses
// the pair (x0,x1) = (hi32(f), lo32(f)) = (0, f) for f < 2^32, key broadcast.
// 32-bit draws return bits1 ^ bits2 (both output words XOR-folded).
__device__ uint32_t threefry_bits_partitionable(uint32_t f) {
  const uint32_t ks0 = 0u;
  const uint32_t ks1 = 42u;
  const uint32_t ks2 = 0x1BD11BDAu ^ 0u ^ 42u;
  uint32_t x0 = 0u;    // high word of flat index (0 for sizes < 2^32)
  uint32_t x1 = f;     // low word of flat index
  x0 += ks0; x1 += ks1;
#define R4(a,b,c,d) \
  x0 += x1; x1 = rotl32(x1,a); x1 ^= x0; \
  x0 += x1; x1 = rotl32(x1,b); x1 ^= x0; \
  x0 += x1; x1 = rotl32(x1,c); x1 ^= x0; \
  x0 += x1; x1 = rotl32(x1,d); x1 ^= x0;
  R4(13u,15u,26u,6u)   x0 += ks1; x1 += ks2 + 1u;
  R4(17u,29u,16u,24u)  x0 += ks2; x1 += ks0 + 2u;
  R4(13u,15u,26u,6u)   x0 += ks0; x1 += ks1 + 3u;
  R4(17u,29u,16u,24u)  x0 += ks1; x1 += ks2 + 4u;
  R4(13u,15u,26u,6u)   x0 += ks2; x1 += ks0 + 5u;
#undef R4
  return x0 ^ x1;
}

__global__ __launch_bounds__(NT) void sampler_kernel(
    const float* __restrict__ logits,
    const float* __restrict__ temperature,
    const int*   __restrict__ top_k,
    const float* __restrict__ top_p,
    const float* __restrict__ min_p,
    const int*   __restrict__ target_ids,
    float*       __restrict__ out)
{
  const int r   = blockIdx.x;
  const int tid = threadIdx.x;
  const float* __restrict__ row = logits + (size_t)r * V_;

  __shared__ unsigned int       s_hist[NBUCK];
  __shared__ unsigned long long s_cand[CAP];
  __shared__ unsigned int       s_candcount;
  __shared__ float              s_wavesum[NT / 64];
  __shared__ unsigned long long s_top[K_];
  __shared__ float              s_g[K_];
  __shared__ float              s_logZ;
  __shared__ int                s_ncand;
  __shared__ unsigned int       s_thrbits;

  for (int i = tid; i < NBUCK; i += NT) s_hist[i] = 0u;
  if (tid < K_) s_top[tid] = 0ull;
  if (tid == 0) s_candcount = 0u;
  __syncthreads();

  const float temp = fmaxf(temperature[r], 0.05f);

  // ---- single streaming pass: sum(exp(x)) + histogram(>2) + candidates(>3)
  float esum = 0.0f;
  const float4* row4 = reinterpret_cast<const float4*>(row);
  for (int i = tid; i < V_ / 4; i += NT) {
    float4 v = row4[i];
    float xs[4] = {v.x, v.y, v.z, v.w};
#pragma unroll
    for (int c = 0; c < 4; ++c) {
      float x = xs[c];
      esum += __expf(x);   // logZ tolerance is ~0.35 abs; fast exp err ~1e-6
      if (x > 2.0f) {
        uint32_t ub = __float_as_uint(x);        // positive floats: bits monotone
        uint32_t bk = (ub - 0x40000000u) >> 13;  // [2,16) -> 3072 buckets
        if (bk > (uint32_t)(NBUCK - 1)) bk = NBUCK - 1;
        atomicAdd(&s_hist[bk], 1u);
        if (x > 3.0f) {
          unsigned int slot = atomicAdd(&s_candcount, 1u);
          if (slot < CAP) {
            float scaled = x / temp;             // identical op to JAX's logits/temp
            uint32_t idx = (uint32_t)(i * 4 + c);
            s_cand[slot] = ((unsigned long long)__float_as_uint(scaled) << 32) |
                           (unsigned long long)(0xFFFFFFFFu - idx);
          }
        }
      }
    }
  }

  // ---- block reduce sum(exp)
  for (int off = 32; off > 0; off >>= 1) esum += __shfl_down(esum, off, 64);
  if ((tid & 63) == 0) s_wavesum[tid >> 6] = esum;
  __syncthreads();
  if (tid == 0) {
    float t = 0.0f;
    for (int w = 0; w < NT / 64; ++w) t += s_wavesum[w];
    s_logZ = logf(t);  // == logsumexp(row) mathematically
    int nc = (int)s_candcount; if (nc > CAP) nc = CAP;
    s_ncand = nc;
  }
  __syncthreads();

  int ncand = s_ncand;
  // ---- fallback (statistically never taken for N(0,1) rows): re-collect with
  // threshold derived from the histogram so that >=64 candidates are gathered.
  if (ncand < K_) {
    if (tid == 0) {
      int cum = 0, tb = 0;
      for (int b2 = NBUCK - 1; b2 >= 0; --b2) {
        cum += (int)s_hist[b2];
        if (cum >= K_) { tb = b2; break; }
      }
      s_thrbits = 0x40000000u + ((uint32_t)tb << 13);
      s_candcount = 0u;
    }
    __syncthreads();
    const float thr = __uint_as_float(s_thrbits);
    for (int i = tid; i < V_; i += NT) {
      float x = row[i];
      if (x >= thr) {
        unsigned int slot = atomicAdd(&s_candcount, 1u);
        if (slot < CAP) {
          float scaled = x / temp;
          s_cand[slot] = ((unsigned long long)__float_as_uint(scaled) << 32) |
                         (unsigned long long)(0xFFFFFFFFu - (uint32_t)i);
        }
      }
    }
    __syncthreads();
    if (tid == 0) { int nc = (int)s_candcount; if (nc > CAP) nc = CAP; s_ncand = nc; }
    __syncthreads();
    ncand = s_ncand;
  }

  // ---- Gumbel noise, replicating jax.random.gumbel(key(42), (256,64), f32)
  if (tid < K_) {
    uint32_t bits = threefry_bits_partitionable((uint32_t)(r * K_ + tid));
    float u01 = __uint_as_float((bits >> 9) | 0x3f800000u) - 1.0f;
    const float tiny = 1.1754943508222875e-38f;
    float u = fmaxf(tiny, u01 * (1.0f - tiny) + tiny);
    s_g[tid] = -logf(-logf(u));
  }

  // ---- perplexity gathers (row is hot in cache)
  if (tid < T_) {
    int tgt = target_ids[r * T_ + tid];
    out[B_ + r * T_ + tid] = s_logZ - row[tgt];
  }

  // ---- rank selection: keys are distinct (unique idx), rank = #greater keys.
  // Reproduces lax.top_k order: value desc, index asc on ties.
  for (int c = tid; c < ncand; c += NT) {
    unsigned long long key = s_cand[c];
    int rank = 0;
    for (int j = 0; j < ncand; ++j) rank += (s_cand[j] > key) ? 1 : 0;
    if (rank < K_) s_top[rank] = key;
  }
  __syncthreads();

  // ---- per-row epilogue (64-wide, serial on lane 0; negligible time)
  if (tid == 0) {
    int kk = top_k[r];
    kk = kk < 1 ? 1 : (kk > K_ ? K_ : kk);
    const float tp = top_p[r], mp = min_p[r];
    const int nn = ncand < K_ ? ncand : K_;

    float e[K_];
    float m = 0.0f, sum = 0.0f;
    for (int i = 0; i < K_; ++i) {
      float v = (i < nn) ? __uint_as_float((uint32_t)(s_top[i] >> 32)) : NEG_INF_;
      if (i >= kk) v = NEG_INF_;
      if (i == 0) m = v;                 // sorted desc & always kept -> max
      e[i] = expf(v - m);                // masked: exp(-1e30) == 0
      sum += e[i];
    }
    float csum = 0.0f, best = -INFINITY;
    int choice = 0;
    const float p0 = e[0] / sum;
    for (int i = 0; i < K_; ++i) {
      float pi = e[i] / sum;
      csum += pi;
      bool keep = (i < kk) && ((csum - pi) < tp) && (pi >= mp * p0);
      if (i == 0) keep = true;
      float fl = keep ? logf(pi + 1e-20f) : NEG_INF_;
      float sc = fl + s_g[i];
      if (sc > best) { best = sc; choice = i; }  // strict '>' == first argmax
    }
    int token = (int)(0xFFFFFFFFu - (uint32_t)(s_top[choice] & 0xFFFFFFFFull));
    out[r] = (float)token;               // ids < 2^24: exact in f32
  }
}

extern "C" void kernel_launch(void* const* d_in, const int* in_sizes, int n_in,
                              void* d_out, int out_size, void* d_ws, size_t ws_size,
                              hipStream_t stream) {
  const float* logits      = (const float*)d_in[0];
  const float* temperature = (const float*)d_in[1];
  const int*   top_k       = (const int*)d_in[2];
  const float* top_p       = (const float*)d_in[3];
  const float* min_p       = (const float*)d_in[4];
  const int*   target_ids  = (const int*)d_in[5];
  float* out = (float*)d_out;
  (void)in_sizes; (void)n_in; (void)out_size; (void)d_ws; (void)ws_size;

  hipLaunchKernelGGL(sampler_kernel, dim3(B_), dim3(NT), 0, stream,
                     logits, temperature, top_k, top_p, min_p, target_ids, out);
}

// Round 3
// 41.376 us; speedup vs baseline: 1.0742x; 1.0742x over previous
//
#include <hip/hip_runtime.h>
#include <stdint.h>

// Problem constants (fixed by the reference setup)
#define B_ 256
#define V_ 128000
#define T_ 16
#define K_ 64
#define NEG_INF_ (-1e30f)

#define CAP   4096     // candidate buffer capacity (E[count]=173 at thr 3.0; tier-2 thr 2.0 -> ~2900)
#define NT    1024     // threads per block (16 waves)

__device__ __forceinline__ uint32_t rotl32(uint32_t x, uint32_t d) {
  return (x << d) | (x >> (32u - d));
}

// JAX threefry2x32, PARTITIONABLE scheme (default since JAX 0.4.30).
// key = jax.random.key(42) -> (k1,k2)=(0,42); element flat index f uses
// counter pair (0, f); 32-bit draws return y0 ^ y1.
__device__ uint32_t threefry_bits_partitionable(uint32_t f) {
  const uint32_t ks0 = 0u;
  const uint32_t ks1 = 42u;
  const uint32_t ks2 = 0x1BD11BDAu ^ 0u ^ 42u;
  uint32_t x0 = 0u;
  uint32_t x1 = f;
  x0 += ks0; x1 += ks1;
#define R4(a,b,c,d) \
  x0 += x1; x1 = rotl32(x1,a); x1 ^= x0; \
  x0 += x1; x1 = rotl32(x1,b); x1 ^= x0; \
  x0 += x1; x1 = rotl32(x1,c); x1 ^= x0; \
  x0 += x1; x1 = rotl32(x1,d); x1 ^= x0;
  R4(13u,15u,26u,6u)   x0 += ks1; x1 += ks2 + 1u;
  R4(17u,29u,16u,24u)  x0 += ks2; x1 += ks0 + 2u;
  R4(13u,15u,26u,6u)   x0 += ks0; x1 += ks1 + 3u;
  R4(17u,29u,16u,24u)  x0 += ks1; x1 += ks2 + 4u;
  R4(13u,15u,26u,6u)   x0 += ks2; x1 += ks0 + 5u;
#undef R4
  return x0 ^ x1;
}

__global__ __launch_bounds__(NT) void sampler_kernel(
    const float* __restrict__ logits,
    const float* __restrict__ temperature,
    const int*   __restrict__ top_k,
    const float* __restrict__ top_p,
    const float* __restrict__ min_p,
    const int*   __restrict__ target_ids,
    float*       __restrict__ out)
{
  const int r   = blockIdx.x;
  const int tid = threadIdx.x;
  const float* __restrict__ row = logits + (size_t)r * V_;

  __shared__ unsigned long long s_cand[CAP];
  __shared__ unsigned int       s_candcount;
  __shared__ float              s_wavesum[NT / 64];
  __shared__ unsigned long long s_top[K_];
  __shared__ float              s_g[K_];
  __shared__ float              s_logZ;
  __shared__ int                s_ncand;

  if (tid < K_) s_top[tid] = 0ull;
  if (tid == 0) s_candcount = 0u;
  __syncthreads();

  const float temp = fmaxf(temperature[r], 0.05f);

  // ---- single streaming pass: sum(exp(x)) + candidate harvest (x > 3.0).
  // 4 independent float4 loads per thread per iteration -> 4x loads in
  // flight per wave (latency hiding); 4 independent exp-sum accumulators.
  float a0 = 0.0f, a1 = 0.0f, a2 = 0.0f, a3 = 0.0f;
  const float4* row4 = reinterpret_cast<const float4*>(row);
  const int nf4 = V_ / 4;  // 32000

#define PROC4(vv, i4) do {                                                     \
    a0 += __expf(vv.x); a1 += __expf(vv.y);                                    \
    a2 += __expf(vv.z); a3 += __expf(vv.w);                                    \
    float mx_ = fmaxf(fmaxf(vv.x, vv.y), fmaxf(vv.z, vv.w));                   \
    if (mx_ > 3.0f) {                                                          \
      float xs_[4] = {vv.x, vv.y, vv.z, vv.w};                                 \
      _Pragma("unroll")                                                        \
      for (int c_ = 0; c_ < 4; ++c_) {                                         \
        if (xs_[c_] > 3.0f) {                                                  \
          unsigned int slot_ = atomicAdd(&s_candcount, 1u);                    \
          if (slot_ < CAP) {                                                   \
            float scaled_ = xs_[c_] / temp;                                    \
            uint32_t idx_ = (uint32_t)((i4) * 4 + c_);                         \
            s_cand[slot_] =                                                    \
              ((unsigned long long)__float_as_uint(scaled_) << 32) |           \
              (unsigned long long)(0xFFFFFFFFu - idx_);                        \
          }                                                                    \
        }                                                                      \
      }                                                                        \
    }                                                                          \
  } while (0)

  int base = 0;
  for (; base + NT * 4 <= nf4; base += NT * 4) {
    const int i0 = base + tid, i1 = i0 + NT, i2 = i1 + NT, i3 = i2 + NT;
    float4 v0 = row4[i0];
    float4 v1 = row4[i1];
    float4 v2 = row4[i2];
    float4 v3 = row4[i3];
    PROC4(v0, i0); PROC4(v1, i1); PROC4(v2, i2); PROC4(v3, i3);
  }
  for (int i = base + tid; i < nf4; i += NT) {
    float4 v = row4[i];
    PROC4(v, i);
  }
#undef PROC4

  // ---- block reduce sum(exp)
  float esum = (a0 + a1) + (a2 + a3);
  for (int off = 32; off > 0; off >>= 1) esum += __shfl_down(esum, off, 64);
  if ((tid & 63) == 0) s_wavesum[tid >> 6] = esum;
  __syncthreads();
  if (tid == 0) {
    float t = 0.0f;
    for (int w = 0; w < NT / 64; ++w) t += s_wavesum[w];
    s_logZ = logf(t);  // == logsumexp(row) mathematically
    int nc = (int)s_candcount; if (nc > CAP) nc = CAP;
    s_ncand = nc;
  }
  __syncthreads();

  int ncand = s_ncand;
  // ---- tiered fallback (statistically unreachable for N(0,1) rows):
  // re-collect with a lower threshold until >= 64 candidates.
  for (int tier = 0; tier < 2 && ncand < K_; ++tier) {
    if (tid == 0) s_candcount = 0u;
    __syncthreads();
    const float thr = (tier == 0) ? 2.0f : -3.0e38f;
    for (int i = tid; i < V_; i += NT) {
      float x = row[i];
      if (x >= thr) {
        unsigned int slot = atomicAdd(&s_candcount, 1u);
        if (slot < CAP) {
          float scaled = x / temp;
          s_cand[slot] = ((unsigned long long)__float_as_uint(scaled) << 32) |
                         (unsigned long long)(0xFFFFFFFFu - (uint32_t)i);
        }
      }
    }
    __syncthreads();
    if (tid == 0) { int nc = (int)s_candcount; if (nc > CAP) nc = CAP; s_ncand = nc; }
    __syncthreads();
    ncand = s_ncand;
  }

  // ---- Gumbel noise, replicating jax.random.gumbel(key(42), (256,64), f32)
  if (tid < K_) {
    uint32_t bits = threefry_bits_partitionable((uint32_t)(r * K_ + tid));
    float u01 = __uint_as_float((bits >> 9) | 0x3f800000u) - 1.0f;
    const float tiny = 1.1754943508222875e-38f;
    float u = fmaxf(tiny, u01 * (1.0f - tiny) + tiny);
    s_g[tid] = -logf(-logf(u));
  }

  // ---- perplexity gathers (row is hot in cache)
  if (tid < T_) {
    int tgt = target_ids[r * T_ + tid];
    out[B_ + r * T_ + tid] = s_logZ - row[tgt];
  }

  // ---- rank selection: keys are distinct (unique idx), rank = #greater keys.
  // Reproduces lax.top_k order: value desc, index asc on ties.
  for (int c = tid; c < ncand; c += NT) {
    unsigned long long key = s_cand[c];
    int rank = 0;
    for (int j = 0; j < ncand; ++j) rank += (s_cand[j] > key) ? 1 : 0;
    if (rank < K_) s_top[rank] = key;
  }
  __syncthreads();

  // ---- per-row epilogue (serial on lane 0; passed bit-exact in round 2 —
  // kept byte-identical: sequential f32 cumsum / sum order matches np ref)
  if (tid == 0) {
    int kk = top_k[r];
    kk = kk < 1 ? 1 : (kk > K_ ? K_ : kk);
    const float tp = top_p[r], mp = min_p[r];
    const int nn = ncand < K_ ? ncand : K_;

    float e[K_];
    float m = 0.0f, sum = 0.0f;
    for (int i = 0; i < K_; ++i) {
      float v = (i < nn) ? __uint_as_float((uint32_t)(s_top[i] >> 32)) : NEG_INF_;
      if (i >= kk) v = NEG_INF_;
      if (i == 0) m = v;                 // sorted desc & always kept -> max
      e[i] = expf(v - m);                // masked: exp(-1e30) == 0
      sum += e[i];
    }
    float csum = 0.0f, best = -INFINITY;
    int choice = 0;
    const float p0 = e[0] / sum;
    for (int i = 0; i < K_; ++i) {
      float pi = e[i] / sum;
      csum += pi;
      bool keep = (i < kk) && ((csum - pi) < tp) && (pi >= mp * p0);
      if (i == 0) keep = true;
      float fl = keep ? logf(pi + 1e-20f) : NEG_INF_;
      float sc = fl + s_g[i];
      if (sc > best) { best = sc; choice = i; }  // strict '>' == first argmax
    }
    int token = (int)(0xFFFFFFFFu - (uint32_t)(s_top[choice] & 0xFFFFFFFFull));
    out[r] = (float)token;               // ids < 2^24: exact in f32
  }
}

extern "C" void kernel_launch(void* const* d_in, const int* in_sizes, int n_in,
                              void* d_out, int out_size, void* d_ws, size_t ws_size,
                              hipStream_t stream) {
  const float* logits      = (const float*)d_in[0];
  const float* temperature = (const float*)d_in[1];
  const int*   top_k       = (const int*)d_in[2];
  const float* top_p       = (const float*)d_in[3];
  const float* min_p       = (const float*)d_in[4];
  const int*   target_ids  = (const int*)d_in[5];
  float* out = (float*)d_out;
  (void)in_sizes; (void)n_in; (void)out_size; (void)d_ws; (void)ws_size;

  hipLaunchKernelGGL(sampler_kernel, dim3(B_), dim3(NT), 0, stream,
                     logits, temperature, top_k, top_p, min_p, target_ids, out);
}